// Round 3
// baseline (6786.607 us; speedup 1.0000x reference)
//
#include <hip/hip_runtime.h>
#include <stdint.h>

// GatingNet via scaled-fp16 split MFMA: x = hi + lo*2^-11 (lo kept normal).
// Products: hi*hi -> C1 ; hi*lo + lo*hi -> C2 ; result = C1 + C2*2^-11.
// Repr residual ~2^-22/product; C2 separated so small terms don't round vs big sum.
// logits = tanh(h @ W1^T + b1) @ W2^T + b2 ; top-2 masked softmax.
// N=131072, H=1024, E=64. Block = 256 thr (4 waves), 64 rows/block.
// GEMM1: N chunked 4x256; per-wave 2 M-tiles x 2 N-tiles of 32x32, BK=32.
// GEMM2: per 64-col quarter, A round-trips LDS in MFMA-A layout.

typedef _Float16 half8  __attribute__((ext_vector_type(8)));
typedef float    f32x16 __attribute__((ext_vector_type(16)));

constexpr int W2S_OFF = 32 * 1024 * 64;  // halves; W1 split = 4M halves, W2 after
constexpr float LO_SCALE   = 2048.0f;
constexpr float LO_UNSCALE = 1.0f / 2048.0f;

__device__ __forceinline__ void f16split(float x, _Float16& hi, _Float16& lo) {
  hi = (_Float16)x;                          // RNE
  lo = (_Float16)((x - (float)hi) * LO_SCALE);  // Sterbenz-exact diff, exact *2^11, RNE
}
__device__ __forceinline__ uint64_t pack4h(_Float16 a, _Float16 b, _Float16 c, _Float16 d) {
  union { _Float16 h[4]; uint64_t u; } x;
  x.h[0] = a; x.h[1] = b; x.h[2] = c; x.h[3] = d;
  return x.u;
}
__device__ __forceinline__ half8 lds8(const _Float16* p) {
  union { uint64_t u[2]; half8 v; } r;
  r.u[0] = *(const uint64_t*)p;
  r.u[1] = *(const uint64_t*)(p + 4);
  return r.v;
}

// ---- pre-split W1/W2 into fp16 hi/lo', staging-friendly layout ----
// W1s: [kt=32][n=1024][hi 32 | lo 32] halves ; W2s: [kt=32][e=64][hi 32 | lo 32]
__global__ void __launch_bounds__(256) split_weights(const float* __restrict__ W1,
                                                     const float* __restrict__ W2,
                                                     _Float16* __restrict__ ws) {
  int gid = (blockIdx.x * 256 + threadIdx.x) * 4;
  const float* src;
  _Float16* dst;
  if (gid < 1024 * 1024) {
    int n = gid >> 10, k = gid & 1023;
    src = W1 + gid;
    dst = ws + ((long)(k >> 5) * 1024 + n) * 64 + (k & 31);
  } else {
    int g2 = gid - 1024 * 1024;
    if (g2 >= 64 * 1024) return;
    int e = g2 >> 10, k = g2 & 1023;
    src = W2 + g2;
    dst = ws + W2S_OFF + ((long)(k >> 5) * 64 + e) * 64 + (k & 31);
  }
  float4 v = *(const float4*)src;
  _Float16 h0, h1, h2, h3, l0, l1, l2, l3;
  f16split(v.x, h0, l0); f16split(v.y, h1, l1);
  f16split(v.z, h2, l2); f16split(v.w, h3, l3);
  *(uint64_t*)dst        = pack4h(h0, h1, h2, h3);
  *(uint64_t*)(dst + 32) = pack4h(l0, l1, l2, l3);
}

// LDS map (halves): sHh[64][36]@0  sHl@2304  sW1h[256][36]@4608  sW1l@13824
//                   sA2h[64][68]@23040  sA2l@27392  (total 31744 = 63488 B)
// sW2h/sW2l alias sHh/sHl during GEMM2; sL (float[64][68]) aliases base at the end.
__global__ void __launch_bounds__(256, 2)
gating_mfma(const float* __restrict__ h, const _Float16* __restrict__ ws,
            const float* __restrict__ b1, const float* __restrict__ b2,
            float* __restrict__ out) {
  __shared__ _Float16 smem[31744];
  _Float16* sHh  = smem;
  _Float16* sHl  = smem + 2304;
  _Float16* sW1h = smem + 4608;
  _Float16* sW1l = smem + 13824;
  _Float16* sA2h = smem + 23040;
  _Float16* sA2l = smem + 27392;
  _Float16* sW2h = smem;         // alias, phase-separated by barriers
  _Float16* sW2l = smem + 2304;
  float* sL = (float*)smem;

  const int t    = threadIdx.x;
  const int w    = t >> 6;
  const int lane = t & 63;
  const int l31  = lane & 31;
  const int lhi  = lane >> 5;
  const int kb   = lhi * 8;
  const long rowbase = (long)blockIdx.x * 64;

  const _Float16* W1s = ws;
  const _Float16* W2s = ws + W2S_OFF;

  const int mt2 = w >> 1, nt2 = w & 1;   // GEMM2 tile of this wave
  f32x16 lacc1, lacc2;
#pragma unroll
  for (int i = 0; i < 16; ++i) { lacc1[i] = 0.0f; lacc2[i] = 0.0f; }
  const float b2v = b2[nt2 * 32 + l31];

  const int srow = t >> 2;        // h staging row
  const int skq  = (t & 3) * 8;   // h staging k-quad

  for (int chunk = 0; chunk < 4; ++chunk) {
    const int cbase = chunk * 256;
    f32x16 acc1[2][2], acc2[2][2];
#pragma unroll
    for (int mt = 0; mt < 2; ++mt)
#pragma unroll
      for (int nt = 0; nt < 2; ++nt)
#pragma unroll
        for (int i = 0; i < 16; ++i) { acc1[mt][nt][i] = 0.0f; acc2[mt][nt][i] = 0.0f; }

    float b1v[2];
    b1v[0] = b1[cbase + w * 32 + l31];
    b1v[1] = b1[cbase + (w + 4) * 32 + l31];

    for (int kt = 0; kt < 32; ++kt) {
      const int kk = kt * 32;
      __syncthreads();
      {  // stage h rows: fp32 -> fp16 hi/lo', [m][k] stride 36
        const float* hp = h + (rowbase + srow) * 1024 + kk + skq;
        float4 a = *(const float4*)hp;
        float4 b = *(const float4*)(hp + 4);
        float xs[8] = {a.x, a.y, a.z, a.w, b.x, b.y, b.z, b.w};
        _Float16 hi[8], lo[8];
#pragma unroll
        for (int j = 0; j < 8; ++j) f16split(xs[j], hi[j], lo[j]);
        _Float16* dh = sHh + srow * 36 + skq;
        _Float16* dl = sHl + srow * 36 + skq;
        *(uint64_t*)(dh)     = pack4h(hi[0], hi[1], hi[2], hi[3]);
        *(uint64_t*)(dh + 4) = pack4h(hi[4], hi[5], hi[6], hi[7]);
        *(uint64_t*)(dl)     = pack4h(lo[0], lo[1], lo[2], lo[3]);
        *(uint64_t*)(dl + 4) = pack4h(lo[4], lo[5], lo[6], lo[7]);
      }
      {  // stage W1 tile: pre-split, 128B contiguous per thread, coalesced
        const uint64_t* src = (const uint64_t*)(W1s + ((long)(kt * 1024 + cbase + t) * 64));
        uint64_t r0 = src[0], r1 = src[1], r2 = src[2], r3 = src[3];
        uint64_t r4 = src[4], r5 = src[5], r6 = src[6], r7 = src[7];
        uint64_t r8 = src[8], r9 = src[9], r10 = src[10], r11 = src[11];
        uint64_t r12 = src[12], r13 = src[13], r14 = src[14], r15 = src[15];
        _Float16* dh = sW1h + t * 36;
        _Float16* dl = sW1l + t * 36;
        *(uint64_t*)(dh + 0)  = r0;  *(uint64_t*)(dh + 4)  = r1;
        *(uint64_t*)(dh + 8)  = r2;  *(uint64_t*)(dh + 12) = r3;
        *(uint64_t*)(dh + 16) = r4;  *(uint64_t*)(dh + 20) = r5;
        *(uint64_t*)(dh + 24) = r6;  *(uint64_t*)(dh + 28) = r7;
        *(uint64_t*)(dl + 0)  = r8;  *(uint64_t*)(dl + 4)  = r9;
        *(uint64_t*)(dl + 8)  = r10; *(uint64_t*)(dl + 12) = r11;
        *(uint64_t*)(dl + 16) = r12; *(uint64_t*)(dl + 20) = r13;
        *(uint64_t*)(dl + 24) = r14; *(uint64_t*)(dl + 28) = r15;
      }
      __syncthreads();
#pragma unroll
      for (int ks = 0; ks < 32; ks += 16) {
        half8 ah[2], al[2], bh[2], bl[2];
#pragma unroll
        for (int mt = 0; mt < 2; ++mt) {
          const _Float16* pa = sHh + (mt * 32 + l31) * 36 + ks + kb;
          ah[mt] = lds8(pa);
          al[mt] = lds8(pa + 2304);
        }
#pragma unroll
        for (int nt = 0; nt < 2; ++nt) {
          const _Float16* pb = sW1h + ((w + 4 * nt) * 32 + l31) * 36 + ks + kb;
          bh[nt] = lds8(pb);
          bl[nt] = lds8(pb + 9216);
        }
#pragma unroll
        for (int mt = 0; mt < 2; ++mt)
#pragma unroll
          for (int nt = 0; nt < 2; ++nt) {
            acc1[mt][nt] = __builtin_amdgcn_mfma_f32_32x32x16_f16(ah[mt], bh[nt], acc1[mt][nt], 0, 0, 0);
            acc2[mt][nt] = __builtin_amdgcn_mfma_f32_32x32x16_f16(ah[mt], bl[nt], acc2[mt][nt], 0, 0, 0);
            acc2[mt][nt] = __builtin_amdgcn_mfma_f32_32x32x16_f16(al[mt], bh[nt], acc2[mt][nt], 0, 0, 0);
          }
      }
    }

    // ---- tanh epilogue + GEMM2, four 64-col quarters of this chunk ----
    for (int q = 0; q < 4; ++q) {
      __syncthreads();  // protect sA2 from previous quarter's reads
      if ((w >> 1) == (q & 1)) {  // this wave owns a tile in quarter q
        const int nt = q >> 1;
        const int colloc = 32 * (w & 1) + l31;
#pragma unroll
        for (int mt = 0; mt < 2; ++mt)
#pragma unroll
          for (int r = 0; r < 16; ++r) {
            const int row = mt * 32 + (r & 3) + 8 * (r >> 2) + 4 * lhi;
            float pre = acc1[mt][nt][r] + acc2[mt][nt][r] * LO_UNSCALE + b1v[nt];
            float v = tanhf(pre);
            _Float16 hv, lv;
            f16split(v, hv, lv);
            sA2h[row * 68 + colloc] = hv;
            sA2l[row * 68 + colloc] = lv;
          }
      }
      for (int k2 = 0; k2 < 64; k2 += 32) {
        __syncthreads();  // sA2 visible / protect sW2 tile
        {  // stage W2 k-tile: wave w copies segment w (32B per thread)
          const int ktg = (cbase + q * 64 + k2) >> 5;
          const uint64_t* src = (const uint64_t*)(W2s + ((long)(ktg * 64 + lane) * 64
                                                          + (w >> 1) * 32 + (w & 1) * 16));
          uint64_t r0 = src[0], r1 = src[1], r2 = src[2], r3 = src[3];
          _Float16* d = ((w >> 1) ? sW2l : sW2h) + lane * 36 + (w & 1) * 16;
          *(uint64_t*)(d + 0) = r0; *(uint64_t*)(d + 4)  = r1;
          *(uint64_t*)(d + 8) = r2; *(uint64_t*)(d + 12) = r3;
        }
        __syncthreads();
#pragma unroll
        for (int ks = 0; ks < 32; ks += 16) {
          const _Float16* pa = sA2h + (mt2 * 32 + l31) * 68 + k2 + ks + kb;
          half8 a2h = lds8(pa), a2l = lds8(pa + 4352);
          const _Float16* pb = sW2h + (nt2 * 32 + l31) * 36 + ks + kb;
          half8 w2h = lds8(pb), w2l = lds8(pb + 2304);
          lacc1 = __builtin_amdgcn_mfma_f32_32x32x16_f16(a2h, w2h, lacc1, 0, 0, 0);
          lacc2 = __builtin_amdgcn_mfma_f32_32x32x16_f16(a2h, w2l, lacc2, 0, 0, 0);
          lacc2 = __builtin_amdgcn_mfma_f32_32x32x16_f16(a2l, w2h, lacc2, 0, 0, 0);
        }
      }
    }
  }

  // ---- logits -> LDS (float), top-2 masked softmax ----
  __syncthreads();
#pragma unroll
  for (int r = 0; r < 16; ++r) {
    const int row = mt2 * 32 + (r & 3) + 8 * (r >> 2) + 4 * lhi;
    sL[row * 68 + nt2 * 32 + l31] = lacc1[r] + lacc2[r] * LO_UNSCALE + b2v;
  }
  __syncthreads();
  {
    const int row = t >> 2;
    const int sub = t & 3;
    float v1 = -1e30f, v2 = -1e30f;
    int i1 = -1, i2 = -1;
#pragma unroll
    for (int j = 0; j < 16; ++j) {
      const float v = sL[row * 68 + sub * 16 + j];
      const int idx = sub * 16 + j;
      if (v > v1) { v2 = v1; i2 = i1; v1 = v; i1 = idx; }
      else if (v > v2) { v2 = v; i2 = idx; }
    }
#pragma unroll
    for (int off = 1; off <= 2; off <<= 1) {
      const float ov1 = __shfl_xor(v1, off);
      const int   oi1 = __shfl_xor(i1, off);
      const float ov2 = __shfl_xor(v2, off);
      const int   oi2 = __shfl_xor(i2, off);
      if (ov1 > v1) {
        if (v1 > ov2) { v2 = v1; i2 = i1; }
        else          { v2 = ov2; i2 = oi2; }
        v1 = ov1; i1 = oi1;
      } else if (ov1 > v2) {
        v2 = ov1; i2 = oi1;
      }
    }
    const float e2 = __expf(v2 - v1);
    const float inv = 1.0f / (1.0f + e2);
    const float p1 = inv, p2 = e2 * inv;
    float* orow = out + (rowbase + row) * 64 + sub * 16;
#pragma unroll
    for (int qq = 0; qq < 4; ++qq) {
      const int idx0 = sub * 16 + qq * 4;
      float4 o;
      o.x = (idx0 + 0 == i1) ? p1 : ((idx0 + 0 == i2) ? p2 : 0.0f);
      o.y = (idx0 + 1 == i1) ? p1 : ((idx0 + 1 == i2) ? p2 : 0.0f);
      o.z = (idx0 + 2 == i1) ? p1 : ((idx0 + 2 == i2) ? p2 : 0.0f);
      o.w = (idx0 + 3 == i1) ? p1 : ((idx0 + 3 == i2) ? p2 : 0.0f);
      *(float4*)(orow + qq * 4) = o;
    }
  }
}

extern "C" void kernel_launch(void* const* d_in, const int* in_sizes, int n_in,
                              void* d_out, int out_size, void* d_ws, size_t ws_size,
                              hipStream_t stream) {
  const float* h  = (const float*)d_in[0];
  const float* W1 = (const float*)d_in[1];
  const float* b1 = (const float*)d_in[2];
  const float* W2 = (const float*)d_in[3];
  const float* b2 = (const float*)d_in[4];
  float* out = (float*)d_out;
  _Float16* ws = (_Float16*)d_ws;  // needs 4.25 MB; re-split every launch (ws re-poisoned)
  split_weights<<<dim3(1088), dim3(256), 0, stream>>>(W1, W2, ws);
  gating_mfma<<<dim3(131072 / 64), dim3(256), 0, stream>>>(h, ws, b1, b2, out);
}